// Round 8
// baseline (96.403 us; speedup 1.0000x reference)
//
#include <hip/hip_runtime.h>
#include <math.h>

#define HH 96
#define WW 96
#define PP 9216   // H*W
#define CCH 256
#define BB 4
#define CH 32

typedef unsigned short u16;
typedef short bf16x8 __attribute__((ext_vector_type(8)));
typedef float f32x4 __attribute__((ext_vector_type(4)));

__device__ __forceinline__ float bf2f(unsigned s) { return __uint_as_float(s << 16); }
__device__ __forceinline__ u16 f2bf(float f) {
  unsigned u = __float_as_uint(f);
  return (u16)((u + 0x7fffu + ((u >> 16) & 1u)) >> 16);
}

typedef __attribute__((address_space(1))) const unsigned int GUI;
typedef __attribute__((address_space(3))) unsigned int LUI;
__device__ __forceinline__ void gload16(const void* g, void* l) {
  __builtin_amdgcn_global_load_lds((GUI*)g, (LUI*)l, 16, 0, 0);
}

// ---------------------------------------------------------------------------
// wcvt: W -> bf16 in per-lane FRAGMENT order so GEMMs load wf directly from
// L2 with one coalesced 16B load per lane (no LDS staging for W).
// granule gidx = ((((kk*2+ks)*4+w)*4+i)*64 + l); holds row=w*64+i*16+(l&15),
// c = kk*64 + (ks*4+(l>>4))*8 .. +7.  mat0=wq at 0, mat1=wo at u16 65536.
// ---------------------------------------------------------------------------
__global__ __launch_bounds__(256)
void wcvt(const float* __restrict__ wq, const float* __restrict__ wo,
          u16* __restrict__ Wbf) {
  int gidx = blockIdx.x * 256 + threadIdx.x;   // 0..16383
  int mat = gidx >> 13;
  int gi = gidx & 8191;
  int l = gi & 63;
  int i = (gi >> 6) & 3;
  int w = (gi >> 8) & 3;
  int ks = (gi >> 10) & 1;
  int kk = (gi >> 11) & 3;
  const float* W = mat ? wo : wq;
  int row = w * 64 + i * 16 + (l & 15);
  int c0 = kk * 64 + (ks * 4 + (l >> 4)) * 8;
  const float* s = W + (size_t)row * CCH + c0;
  float4 a = *(const float4*)s;
  float4 b = *(const float4*)(s + 4);
  uint4 u;
  u.x = (unsigned)f2bf(a.x) | ((unsigned)f2bf(a.y) << 16);
  u.y = (unsigned)f2bf(a.z) | ((unsigned)f2bf(a.w) << 16);
  u.z = (unsigned)f2bf(b.x) | ((unsigned)f2bf(b.y) << 16);
  u.w = (unsigned)f2bf(b.z) | ((unsigned)f2bf(b.w) << 16);
  *(uint4*)(Wbf + (size_t)gidx * 8) = u;
}

// ---------------------------------------------------------------------------
// Fused projection GEMM v2: f32 NCHW in -> bf16 channel-last out.
// W from L2 (fragment-ordered), X via double-buffered f32 LDS transpose
// Tt[2][64][68] (16B-aligned rows, granule-XOR swizzle), ONE barrier/K-step,
// next K-step's X loads issued before the MFMA phase (T14).
// ---------------------------------------------------------------------------
#define TSTR 68
__global__ __launch_bounds__(256, 3)
void gemm_qkvf(const float* __restrict__ qin, const float* __restrict__ kin,
               const float* __restrict__ vin, const u16* __restrict__ Wbf,
               u16* __restrict__ Xcl) {
  __shared__ float Tt[2][64][TSTR];   // 34.8 KB
  const int t = threadIdx.x;
  const int w = t >> 6, l = t & 63;
  const int lr = l & 15, lg = l >> 4;
  const int pblk = blockIdx.x * 64;
  const int z = blockIdx.z;
  const int b = z & 3, which = z >> 2;
  const float* Xf = ((which == 0) ? qin : (which == 1) ? kin : vin) + (size_t)b * CCH * PP;
  u16* Y = Xcl + (size_t)z * ((size_t)PP * CCH);

  const int sw_r = ((lr >> 2) & 3) << 3;  // read-side granule swizzle
  const int cswz = (lr & 3) << 3;         // write-side: p=lr*4+j -> (p>>2)&3 = lr&3

  f32x4 acc[4][4];
#pragma unroll
  for (int mi = 0; mi < 4; mi++)
#pragma unroll
    for (int ni = 0; ni < 4; ni++) acc[mi][ni] = (f32x4){0.f, 0.f, 0.f, 0.f};

  float4 xr[4];
  auto loadX = [&](int kk) {
#pragma unroll
    for (int rr = 0; rr < 4; rr++) {
      int cc = kk * 64 + w * 4 + lg + 16 * rr;
      xr[rr] = *(const float4*)(Xf + (size_t)cc * PP + pblk + lr * 4);
    }
  };
  auto writeT = [&](int buf) {
#pragma unroll
    for (int rr = 0; rr < 4; rr++) {
      int cs = (w * 4 + lg + 16 * rr) ^ cswz;
      Tt[buf][lr * 4 + 0][cs] = xr[rr].x;
      Tt[buf][lr * 4 + 1][cs] = xr[rr].y;
      Tt[buf][lr * 4 + 2][cs] = xr[rr].z;
      Tt[buf][lr * 4 + 3][cs] = xr[rr].w;
    }
  };
  auto mma = [&](int kk, int cur) {
#pragma unroll
    for (int ks = 0; ks < 2; ks++) {
      bf16x8 wf[4], xf[4];
#pragma unroll
      for (int i = 0; i < 4; i++) {
        size_t go = ((((size_t)(kk * 2 + ks) * 4 + w) * 4 + i) * 64 + l) * 8;
        wf[i] = *(const bf16x8*)(Wbf + go);
      }
#pragma unroll
      for (int i = 0; i < 4; i++) {
        int row = i * 16 + lr;
        int c0 = (ks * 32 + lg * 8) ^ sw_r;
        const float* tp = &Tt[cur][row][c0];
        float4 A = *(const float4*)tp;
        float4 Bv = *(const float4*)(tp + 4);
        bf16x8 x;
        x[0] = (short)f2bf(A.x);  x[1] = (short)f2bf(A.y);
        x[2] = (short)f2bf(A.z);  x[3] = (short)f2bf(A.w);
        x[4] = (short)f2bf(Bv.x); x[5] = (short)f2bf(Bv.y);
        x[6] = (short)f2bf(Bv.z); x[7] = (short)f2bf(Bv.w);
        xf[i] = x;
      }
#pragma unroll
      for (int mi = 0; mi < 4; mi++)
#pragma unroll
        for (int ni = 0; ni < 4; ni++)
          acc[mi][ni] = __builtin_amdgcn_mfma_f32_16x16x32_bf16(
              wf[mi], xf[ni], acc[mi][ni], 0, 0, 0);
    }
  };

  loadX(0);
  writeT(0);
  __syncthreads();
#pragma unroll
  for (int kk = 0; kk < 4; kk++) {
    if (kk < 3) loadX(kk + 1);        // in flight during MFMA phase
    mma(kk, kk & 1);
    if (kk < 3) {
      writeT((kk + 1) & 1);           // other buffer: no WAR on current readers
      __syncthreads();                // one barrier per K-step
    }
  }

  // epilogue: D[o][p] -> bf16 channel-last
#pragma unroll
  for (int mi = 0; mi < 4; mi++)
#pragma unroll
    for (int ni = 0; ni < 4; ni++) {
      int o = w * 64 + mi * 16 + lg * 4;
      int p = pblk + ni * 16 + lr;
      f32x4 a = acc[mi][ni];
      uint2 u;
      u.x = (unsigned)f2bf(a[0]) | ((unsigned)f2bf(a[1]) << 16);
      u.y = (unsigned)f2bf(a[2]) | ((unsigned)f2bf(a[3]) << 16);
      *(uint2*)(Y + (size_t)p * CCH + o) = u;
    }
}

// ---------------------------------------------------------------------------
// Out-projection GEMM v2: bf16 CL in -> f32 NCHW + bias. W from L2 (fragment-
// ordered W2o); only X staged in LDS (8 KB) via global_load_lds.
// ---------------------------------------------------------------------------
__global__ __launch_bounds__(256)
void gemm_out_m(const u16* __restrict__ Xbuf, const u16* __restrict__ Wbf,
                const float* __restrict__ bias, float* __restrict__ outY) {
  __shared__ u16 Xl[64 * 64];   // 8 KB
  const int t = threadIdx.x;
  const int w = t >> 6, l = t & 63;
  const int lr = l & 15, lg = l >> 4;
  const int pblk = blockIdx.x * 64;
  const int z = blockIdx.z;
  const u16* Xb = Xbuf + (size_t)z * ((size_t)PP * CCH);

  f32x4 acc[4][4];
#pragma unroll
  for (int mi = 0; mi < 4; mi++)
#pragma unroll
    for (int ni = 0; ni < 4; ni++) acc[mi][ni] = (f32x4){0.f, 0.f, 0.f, 0.f};

  for (int kk = 0; kk < 4; kk++) {
    const int c0 = kk * 64;
#pragma unroll
    for (int i = 0; i < 2; i++) {
      int r0 = (w * 2 + i) * 8;
      int row = r0 + (l >> 3);
      int gs = (l & 7) ^ (row & 7);
      gload16(Xb + (size_t)(pblk + row) * CCH + c0 + gs * 8, (void*)&Xl[r0 * 64]);
    }
    __syncthreads();
#pragma unroll
    for (int ks = 0; ks < 2; ks++) {
      const int g = ks * 4 + lg;
      bf16x8 wf[4], xf[4];
#pragma unroll
      for (int i = 0; i < 4; i++) {
        size_t go = ((((size_t)(kk * 2 + ks) * 4 + w) * 4 + i) * 64 + l) * 8;
        wf[i] = *(const bf16x8*)(Wbf + go);
      }
#pragma unroll
      for (int i = 0; i < 4; i++) {
        int row = i * 16 + lr;
        xf[i] = *(const bf16x8*)&Xl[row * 64 + ((g ^ (row & 7)) << 3)];
      }
#pragma unroll
      for (int mi = 0; mi < 4; mi++)
#pragma unroll
        for (int ni = 0; ni < 4; ni++)
          acc[mi][ni] = __builtin_amdgcn_mfma_f32_16x16x32_bf16(
              xf[mi], wf[ni], acc[mi][ni], 0, 0, 0);
    }
    __syncthreads();
  }
#pragma unroll
  for (int ni = 0; ni < 4; ni++) {
    int o = w * 64 + ni * 16 + lr;
    float bv = bias[o];
#pragma unroll
    for (int mi = 0; mi < 4; mi++) {
      int p = pblk + mi * 16 + lg * 4;
      f32x4 a = acc[mi][ni];
      float4 st = {a[0] + bv, a[1] + bv, a[2] + bv, a[3] + bv};
      *(float4*)(outY + ((size_t)z * CCH + o) * PP + p) = st;
    }
  }
}

// ---------------------------------------------------------------------------
// Attention, single-barrier (unchanged from R7 — ~14 us).
// ---------------------------------------------------------------------------
#define TX 32
#define TY 4
#define HX 34
#define HY 6
#define NHP (HX * HY)
#define NGR (NHP * 4)
#define ARND 4

__device__ __forceinline__ void fma8(const uint4 u, const float* qp, float& s) {
  s = fmaf(qp[0], bf2f(u.x & 0xffffu), s);
  s = fmaf(qp[1], bf2f(u.x >> 16), s);
  s = fmaf(qp[2], bf2f(u.y & 0xffffu), s);
  s = fmaf(qp[3], bf2f(u.y >> 16), s);
  s = fmaf(qp[4], bf2f(u.z & 0xffffu), s);
  s = fmaf(qp[5], bf2f(u.z >> 16), s);
  s = fmaf(qp[6], bf2f(u.w & 0xffffu), s);
  s = fmaf(qp[7], bf2f(u.w >> 16), s);
}
__device__ __forceinline__ void acc8(const uint4 u, float gv, float* op) {
  op[0] = fmaf(gv, bf2f(u.x & 0xffffu), op[0]);
  op[1] = fmaf(gv, bf2f(u.x >> 16), op[1]);
  op[2] = fmaf(gv, bf2f(u.y & 0xffffu), op[2]);
  op[3] = fmaf(gv, bf2f(u.y >> 16), op[3]);
  op[4] = fmaf(gv, bf2f(u.z & 0xffffu), op[4]);
  op[5] = fmaf(gv, bf2f(u.z >> 16), op[5]);
  op[6] = fmaf(gv, bf2f(u.w & 0xffffu), op[6]);
  op[7] = fmaf(gv, bf2f(u.w >> 16), op[7]);
}

__global__ __launch_bounds__(256)
void attn_1b(const u16* __restrict__ Kt, const u16* __restrict__ Vt,
             u16* __restrict__ Qt, const float* __restrict__ pe_dw,
             const float* __restrict__ pe_pw) {
  __shared__ __align__(16) u16 kl[NHP * 32];
  __shared__ __align__(16) u16 vl[NHP * 32];
  __shared__ float coef[81];
  const int t = threadIdx.x;
  if (t < 81) coef[t] = pe_pw[t] * pe_dw[t % 9];

  const int lx = t & 31;
  const int h2 = (t >> 5) & 1;
  const int ly = t >> 6;
  const int x0 = blockIdx.x * TX;
  const int y0 = blockIdx.y * TY;
  const int b = blockIdx.z >> 3;
  const int h = blockIdx.z & 7;
  const size_t nbase = (size_t)b * PP * CCH + h * CH;
  const int p = (y0 + ly) * WW + (x0 + lx);
  const size_t pixhalf = nbase + (size_t)p * CCH + h2 * 16;

  uint4 kg[ARND], vg[ARND];
#pragma unroll
  for (int r = 0; r < ARND; r++) {
    int s = t + r * 256;
    int pix = s >> 2, g = s & 3;
    int hy = pix / HX, hx = pix - hy * HX;
    int gx = x0 - 1 + hx, gy = y0 - 1 + hy;
    bool ok = (s < NGR) & (gx >= 0) & (gx < WW) & (gy >= 0) & (gy < HH);
    uint4 u = make_uint4(0u, 0u, 0u, 0u);
    if (ok) u = *(const uint4*)(Kt + nbase + (size_t)(gy * WW + gx) * CCH + g * 8);
    kg[r] = u;
  }
#pragma unroll
  for (int r = 0; r < ARND; r++) {
    int s = t + r * 256;
    int pix = s >> 2, g = s & 3;
    int hy = pix / HX, hx = pix - hy * HX;
    int gx = x0 - 1 + hx, gy = y0 - 1 + hy;
    bool ok = (s < NGR) & (gx >= 0) & (gx < WW) & (gy >= 0) & (gy < HH);
    uint4 u = make_uint4(0u, 0u, 0u, 0u);
    if (ok) u = *(const uint4*)(Vt + nbase + (size_t)(gy * WW + gx) * CCH + g * 8);
    vg[r] = u;
  }
  uint4 q0 = *(const uint4*)(Qt + pixhalf);
  uint4 q1 = *(const uint4*)(Qt + pixhalf + 8);

#pragma unroll
  for (int r = 0; r < ARND; r++) {
    int s = t + r * 256;
    if (s < NGR) {
      int pix = s >> 2, g = s & 3;
      *(uint4*)(&kl[pix * 32 + (((g + (pix >> 1)) & 3) << 3)]) = kg[r];
    }
  }
#pragma unroll
  for (int r = 0; r < ARND; r++) {
    int s = t + r * 256;
    if (s < NGR) {
      int pix = s >> 2, g = s & 3;
      *(uint4*)(&vl[pix * 32 + (((g + (pix >> 1)) & 3) << 3)]) = vg[r];
    }
  }
  __syncthreads();

  float qh[16];
  qh[0] = bf2f(q0.x & 0xffffu); qh[1] = bf2f(q0.x >> 16);
  qh[2] = bf2f(q0.y & 0xffffu); qh[3] = bf2f(q0.y >> 16);
  qh[4] = bf2f(q0.z & 0xffffu); qh[5] = bf2f(q0.z >> 16);
  qh[6] = bf2f(q0.w & 0xffffu); qh[7] = bf2f(q0.w >> 16);
  qh[8] = bf2f(q1.x & 0xffffu); qh[9] = bf2f(q1.x >> 16);
  qh[10] = bf2f(q1.y & 0xffffu); qh[11] = bf2f(q1.y >> 16);
  qh[12] = bf2f(q1.z & 0xffffu); qh[13] = bf2f(q1.z >> 16);
  qh[14] = bf2f(q1.w & 0xffffu); qh[15] = bf2f(q1.w >> 16);

  float f[9];
#pragma unroll
  for (int kk = 0; kk < 9; kk++) {
    int pix = (ly + kk / 3) * HX + lx + kk % 3;
    int ga = h2 * 2;
    uint4 ka = *(const uint4*)(&kl[pix * 32 + (((ga + (pix >> 1)) & 3) << 3)]);
    uint4 kb = *(const uint4*)(&kl[pix * 32 + (((ga + 1 + (pix >> 1)) & 3) << 3)]);
    float s = 0.f;
    fma8(ka, qh, s);
    fma8(kb, qh + 8, s);
    f[kk] = s + __shfl_xor(s, 32, 64);
  }

  float g[9], m = -1e30f;
#pragma unroll
  for (int k2 = 0; k2 < 9; k2++) {
    float s = 0.f;
#pragma unroll
    for (int kk = 0; kk < 9; kk++) s = fmaf(coef[k2 * 9 + kk], f[kk], s);
    g[k2] = s;
    m = fmaxf(m, s);
  }
  float ssum = 0.f;
#pragma unroll
  for (int k2 = 0; k2 < 9; k2++) {
    g[k2] = __expf(g[k2] - m);
    ssum += g[k2];
  }
  float inv = 1.f / ssum;
#pragma unroll
  for (int k2 = 0; k2 < 9; k2++) g[k2] *= inv;

  float oh[16];
#pragma unroll
  for (int j = 0; j < 16; j++) oh[j] = 0.f;
#pragma unroll
  for (int kk = 0; kk < 9; kk++) {
    int pix = (ly + kk / 3) * HX + lx + kk % 3;
    int ga = h2 * 2;
    uint4 va = *(const uint4*)(&vl[pix * 32 + (((ga + (pix >> 1)) & 3) << 3)]);
    uint4 vb = *(const uint4*)(&vl[pix * 32 + (((ga + 1 + (pix >> 1)) & 3) << 3)]);
    acc8(va, g[kk], oh);
    acc8(vb, g[kk], oh + 8);
  }
  uint4 s0, s1;
  s0.x = (unsigned)f2bf(oh[0]) | ((unsigned)f2bf(oh[1]) << 16);
  s0.y = (unsigned)f2bf(oh[2]) | ((unsigned)f2bf(oh[3]) << 16);
  s0.z = (unsigned)f2bf(oh[4]) | ((unsigned)f2bf(oh[5]) << 16);
  s0.w = (unsigned)f2bf(oh[6]) | ((unsigned)f2bf(oh[7]) << 16);
  s1.x = (unsigned)f2bf(oh[8]) | ((unsigned)f2bf(oh[9]) << 16);
  s1.y = (unsigned)f2bf(oh[10]) | ((unsigned)f2bf(oh[11]) << 16);
  s1.z = (unsigned)f2bf(oh[12]) | ((unsigned)f2bf(oh[13]) << 16);
  s1.w = (unsigned)f2bf(oh[14]) | ((unsigned)f2bf(oh[15]) << 16);
  *(uint4*)(Qt + pixhalf) = s0;
  *(uint4*)(Qt + pixhalf + 8) = s1;
}

// ---------------------------------------------------------------------------
extern "C" void kernel_launch(void* const* d_in, const int* in_sizes, int n_in,
                              void* d_out, int out_size, void* d_ws, size_t ws_size,
                              hipStream_t stream) {
  const float* q     = (const float*)d_in[0];
  const float* k     = (const float*)d_in[1];
  const float* v     = (const float*)d_in[2];
  const float* wq    = (const float*)d_in[3];
  const float* pe_dw = (const float*)d_in[4];
  const float* pe_pw = (const float*)d_in[5];
  const float* wo    = (const float*)d_in[6];
  const float* bo    = (const float*)d_in[7];
  float* out = (float*)d_out;

  const size_t seg = (size_t)BB * PP * CCH;
  u16* Xcl = (u16*)d_ws;                 // 3*seg bf16: q,k,v projections
  u16* Wbf = Xcl + 3 * seg;              // 131072 bf16: W2(wq) | W2(wo)

  wcvt<<<64, 256, 0, stream>>>(wq, wo, Wbf);

  gemm_qkvf<<<dim3(PP / 64, 1, 12), 256, 0, stream>>>(q, k, v, Wbf, Xcl);

  u16* Qs = Xcl;
  u16* Ks = Xcl + seg;
  u16* Vs = Xcl + 2 * seg;
  attn_1b<<<dim3(WW / TX, HH / TY, BB * 8), 256, 0, stream>>>(Ks, Vs, Qs, pe_dw, pe_pw);

  gemm_out_m<<<dim3(PP / 64, 1, BB), 256, 0, stream>>>(Qs, Wbf + 65536, bo, out);
}

// Round 9
// 90.425 us; speedup vs baseline: 1.0661x; 1.0661x over previous
//
#include <hip/hip_runtime.h>
#include <math.h>

#define HH 96
#define WW 96
#define PP 9216   // H*W
#define CCH 256
#define BB 4
#define CH 32

typedef unsigned short u16;
typedef short bf16x8 __attribute__((ext_vector_type(8)));
typedef float f32x4 __attribute__((ext_vector_type(4)));

__device__ __forceinline__ float bf2f(unsigned s) { return __uint_as_float(s << 16); }
__device__ __forceinline__ u16 f2bf(float f) {
  unsigned u = __float_as_uint(f);
  return (u16)((u + 0x7fffu + ((u >> 16) & 1u)) >> 16);
}

typedef __attribute__((address_space(1))) const unsigned int GUI;
typedef __attribute__((address_space(3))) unsigned int LUI;
__device__ __forceinline__ void gload16(const void* g, void* l) {
  __builtin_amdgcn_global_load_lds((GUI*)g, (LUI*)l, 16, 0, 0);
}

// ---------------------------------------------------------------------------
// wcvt: W -> bf16 in per-lane FRAGMENT order (one coalesced 16B L2 load per
// lane per frag in the GEMMs; W never touches LDS). Unchanged from R8.
// ---------------------------------------------------------------------------
__global__ __launch_bounds__(256)
void wcvt(const float* __restrict__ wq, const float* __restrict__ wo,
          u16* __restrict__ Wbf) {
  int gidx = blockIdx.x * 256 + threadIdx.x;   // 0..16383
  int mat = gidx >> 13;
  int gi = gidx & 8191;
  int l = gi & 63;
  int i = (gi >> 6) & 3;
  int w = (gi >> 8) & 3;
  int ks = (gi >> 10) & 1;
  int kk = (gi >> 11) & 3;
  const float* W = mat ? wo : wq;
  int row = w * 64 + i * 16 + (l & 15);
  int c0 = kk * 64 + (ks * 4 + (l >> 4)) * 8;
  const float* s = W + (size_t)row * CCH + c0;
  float4 a = *(const float4*)s;
  float4 b = *(const float4*)(s + 4);
  uint4 u;
  u.x = (unsigned)f2bf(a.x) | ((unsigned)f2bf(a.y) << 16);
  u.y = (unsigned)f2bf(a.z) | ((unsigned)f2bf(a.w) << 16);
  u.z = (unsigned)f2bf(b.x) | ((unsigned)f2bf(b.y) << 16);
  u.w = (unsigned)f2bf(b.z) | ((unsigned)f2bf(b.w) << 16);
  *(uint4*)(Wbf + (size_t)gidx * 8) = u;
}

// ---------------------------------------------------------------------------
// Fused projection GEMM v3 — SINGLE STAGE, SINGLE BARRIER.
// Whole X tile (64p x 256c) staged once: 16 f32 global loads per thread all
// in flight, shfl 4x4 transpose + cvt, bf16 LDS rows padded to 264 u16
// (528B stride -> b128 reads at bank floor). One barrier, then 128 MFMA/wave
// with W direct from L2 (fragment order). Zero further syncs.
// ---------------------------------------------------------------------------
#define XROW 264
__global__ __launch_bounds__(256)
void gemm_qkvf(const float* __restrict__ qin, const float* __restrict__ kin,
               const float* __restrict__ vin, const u16* __restrict__ Wbf,
               u16* __restrict__ Xcl) {
  __shared__ u16 Xb[64 * XROW];   // 33,792 B
  const int t = threadIdx.x;
  const int w = t >> 6, l = t & 63;
  const int lr = l & 15, lg = l >> 4;
  const int pblk = blockIdx.x * 64;
  const int z = blockIdx.z;
  const int b = z & 3, which = z >> 2;
  const float* Xf = ((which == 0) ? qin : (which == 1) ? kin : vin) + (size_t)b * CCH * PP;
  u16* Y = Xcl + (size_t)z * ((size_t)PP * CCH);

  // ---- stage: issue ALL 16 loads (wave covers c = w*64 .. w*64+63) ----
  float4 xr[16];
#pragma unroll
  for (int rr = 0; rr < 16; rr++) {
    int cc = w * 64 + rr * 4 + lg;
    xr[rr] = *(const float4*)(Xf + (size_t)cc * PP + pblk + lr * 4);
  }
  // ---- transpose 4x4 across lg-lanes (R7-verified), cvt, LDS write ----
#pragma unroll
  for (int rr = 0; rr < 16; rr++) {
    float r0 = xr[rr].x, r1 = xr[rr].y, r2 = xr[rr].z, r3 = xr[rr].w;
    bool b0 = (lg & 1), b1 = (lg & 2);
    float s0 = b0 ? r0 : r1;
    float s1 = b0 ? r2 : r3;
    float u0 = __shfl_xor(s0, 16, 64);
    float u1 = __shfl_xor(s1, 16, 64);
    float m0 = b0 ? u0 : r0;
    float m1 = b0 ? r1 : u0;
    float m2 = b0 ? u1 : r2;
    float m3 = b0 ? r3 : u1;
    float s2 = b1 ? m0 : m2;
    float s3 = b1 ? m1 : m3;
    float w0 = __shfl_xor(s2, 32, 64);
    float w1 = __shfl_xor(s3, 32, 64);
    float o0 = b1 ? w0 : m0;
    float o1 = b1 ? w1 : m1;
    float o2 = b1 ? m2 : w0;
    float o3 = b1 ? m3 : w1;
    // lane holds c = cbase..cbase+3 of p-row pl
    int cbase = w * 64 + rr * 4;
    int pl = lr * 4 + lg;
    unsigned lo = (unsigned)f2bf(o0) | ((unsigned)f2bf(o1) << 16);
    unsigned hi = (unsigned)f2bf(o2) | ((unsigned)f2bf(o3) << 16);
    *(uint2*)(&Xb[pl * XROW + cbase]) = make_uint2(lo, hi);
  }
  __syncthreads();   // the ONE barrier

  f32x4 acc[4][4];
#pragma unroll
  for (int mi = 0; mi < 4; mi++)
#pragma unroll
    for (int ni = 0; ni < 4; ni++) acc[mi][ni] = (f32x4){0.f, 0.f, 0.f, 0.f};

  // ---- 128 MFMA per wave, no syncs: W from L2, X from LDS ----
#pragma unroll
  for (int kk = 0; kk < 4; kk++)
#pragma unroll
    for (int ks = 0; ks < 2; ks++) {
      const int q = kk * 8 + ks * 4 + lg;
      bf16x8 wf[4], xf[4];
#pragma unroll
      for (int i = 0; i < 4; i++) {
        size_t go = ((((size_t)(kk * 2 + ks) * 4 + w) * 4 + i) * 64 + l) * 8;
        wf[i] = *(const bf16x8*)(Wbf + go);
      }
#pragma unroll
      for (int i = 0; i < 4; i++) {
        int row = i * 16 + lr;
        xf[i] = *(const bf16x8*)&Xb[row * XROW + q * 8];
      }
#pragma unroll
      for (int mi = 0; mi < 4; mi++)
#pragma unroll
        for (int ni = 0; ni < 4; ni++)
          acc[mi][ni] = __builtin_amdgcn_mfma_f32_16x16x32_bf16(
              wf[mi], xf[ni], acc[mi][ni], 0, 0, 0);
    }

  // epilogue: D[o][p] -> bf16 channel-last
#pragma unroll
  for (int mi = 0; mi < 4; mi++)
#pragma unroll
    for (int ni = 0; ni < 4; ni++) {
      int o = w * 64 + mi * 16 + lg * 4;
      int p = pblk + ni * 16 + lr;
      f32x4 a = acc[mi][ni];
      uint2 u;
      u.x = (unsigned)f2bf(a[0]) | ((unsigned)f2bf(a[1]) << 16);
      u.y = (unsigned)f2bf(a[2]) | ((unsigned)f2bf(a[3]) << 16);
      *(uint2*)(Y + (size_t)p * CCH + o) = u;
    }
}

// ---------------------------------------------------------------------------
// Out-projection GEMM v3 — SINGLE STAGE, SINGLE BARRIER.
// Whole X tile staged via 8 gload16/thread (linear dest, low-3-bit XOR
// pre-swizzled source), one barrier, 128 MFMA/wave, f32 NCHW + bias out.
// ---------------------------------------------------------------------------
__global__ __launch_bounds__(256)
void gemm_out_m(const u16* __restrict__ Xbuf, const u16* __restrict__ Wbf,
                const float* __restrict__ bias, float* __restrict__ outY) {
  __shared__ u16 Xl[64 * 256];   // 32 KB, rows 512B
  const int t = threadIdx.x;
  const int w = t >> 6, l = t & 63;
  const int lr = l & 15, lg = l >> 4;
  const int pblk = blockIdx.x * 64;
  const int z = blockIdx.z;
  const u16* Xb = Xbuf + (size_t)z * ((size_t)PP * CCH);

  // ---- stage all 2048 granules (8 per thread), source pre-swizzled ----
#pragma unroll
  for (int r = 0; r < 8; r++) {
    int G = r * 256 + t;
    int row = G >> 5, g = G & 31;
    int gs = (g & 24) | ((g & 7) ^ (row & 7));
    gload16(Xb + (size_t)(pblk + row) * CCH + gs * 8, (void*)&Xl[(size_t)G * 8]);
  }
  __syncthreads();   // the ONE barrier (drains vmcnt)

  f32x4 acc[4][4];
#pragma unroll
  for (int mi = 0; mi < 4; mi++)
#pragma unroll
    for (int ni = 0; ni < 4; ni++) acc[mi][ni] = (f32x4){0.f, 0.f, 0.f, 0.f};

#pragma unroll
  for (int kk = 0; kk < 4; kk++)
#pragma unroll
    for (int ks = 0; ks < 2; ks++) {
      const int q = kk * 8 + ks * 4 + lg;
      bf16x8 wf[4], xf[4];
#pragma unroll
      for (int i = 0; i < 4; i++) {
        size_t go = ((((size_t)(kk * 2 + ks) * 4 + w) * 4 + i) * 64 + l) * 8;
        wf[i] = *(const bf16x8*)(Wbf + go);
      }
#pragma unroll
      for (int i = 0; i < 4; i++) {
        int row = i * 16 + lr;
        int qp = (q & 24) | ((q & 7) ^ (row & 7));
        xf[i] = *(const bf16x8*)&Xl[row * 256 + qp * 8];
      }
#pragma unroll
      for (int mi = 0; mi < 4; mi++)
#pragma unroll
        for (int ni = 0; ni < 4; ni++)
          acc[mi][ni] = __builtin_amdgcn_mfma_f32_16x16x32_bf16(
              xf[mi], wf[ni], acc[mi][ni], 0, 0, 0);
    }

#pragma unroll
  for (int ni = 0; ni < 4; ni++) {
    int o = w * 64 + ni * 16 + lr;
    float bv = bias[o];
#pragma unroll
    for (int mi = 0; mi < 4; mi++) {
      int p = pblk + mi * 16 + lg * 4;
      f32x4 a = acc[mi][ni];
      float4 st = {a[0] + bv, a[1] + bv, a[2] + bv, a[3] + bv};
      *(float4*)(outY + ((size_t)z * CCH + o) * PP + p) = st;
    }
  }
}

// ---------------------------------------------------------------------------
// Attention, single-barrier (unchanged from R7 — ~14 us).
// ---------------------------------------------------------------------------
#define TX 32
#define TY 4
#define HX 34
#define HY 6
#define NHP (HX * HY)
#define NGR (NHP * 4)
#define ARND 4

__device__ __forceinline__ void fma8(const uint4 u, const float* qp, float& s) {
  s = fmaf(qp[0], bf2f(u.x & 0xffffu), s);
  s = fmaf(qp[1], bf2f(u.x >> 16), s);
  s = fmaf(qp[2], bf2f(u.y & 0xffffu), s);
  s = fmaf(qp[3], bf2f(u.y >> 16), s);
  s = fmaf(qp[4], bf2f(u.z & 0xffffu), s);
  s = fmaf(qp[5], bf2f(u.z >> 16), s);
  s = fmaf(qp[6], bf2f(u.w & 0xffffu), s);
  s = fmaf(qp[7], bf2f(u.w >> 16), s);
}
__device__ __forceinline__ void acc8(const uint4 u, float gv, float* op) {
  op[0] = fmaf(gv, bf2f(u.x & 0xffffu), op[0]);
  op[1] = fmaf(gv, bf2f(u.x >> 16), op[1]);
  op[2] = fmaf(gv, bf2f(u.y & 0xffffu), op[2]);
  op[3] = fmaf(gv, bf2f(u.y >> 16), op[3]);
  op[4] = fmaf(gv, bf2f(u.z & 0xffffu), op[4]);
  op[5] = fmaf(gv, bf2f(u.z >> 16), op[5]);
  op[6] = fmaf(gv, bf2f(u.w & 0xffffu), op[6]);
  op[7] = fmaf(gv, bf2f(u.w >> 16), op[7]);
}

__global__ __launch_bounds__(256)
void attn_1b(const u16* __restrict__ Kt, const u16* __restrict__ Vt,
             u16* __restrict__ Qt, const float* __restrict__ pe_dw,
             const float* __restrict__ pe_pw) {
  __shared__ __align__(16) u16 kl[NHP * 32];
  __shared__ __align__(16) u16 vl[NHP * 32];
  __shared__ float coef[81];
  const int t = threadIdx.x;
  if (t < 81) coef[t] = pe_pw[t] * pe_dw[t % 9];

  const int lx = t & 31;
  const int h2 = (t >> 5) & 1;
  const int ly = t >> 6;
  const int x0 = blockIdx.x * TX;
  const int y0 = blockIdx.y * TY;
  const int b = blockIdx.z >> 3;
  const int h = blockIdx.z & 7;
  const size_t nbase = (size_t)b * PP * CCH + h * CH;
  const int p = (y0 + ly) * WW + (x0 + lx);
  const size_t pixhalf = nbase + (size_t)p * CCH + h2 * 16;

  uint4 kg[ARND], vg[ARND];
#pragma unroll
  for (int r = 0; r < ARND; r++) {
    int s = t + r * 256;
    int pix = s >> 2, g = s & 3;
    int hy = pix / HX, hx = pix - hy * HX;
    int gx = x0 - 1 + hx, gy = y0 - 1 + hy;
    bool ok = (s < NGR) & (gx >= 0) & (gx < WW) & (gy >= 0) & (gy < HH);
    uint4 u = make_uint4(0u, 0u, 0u, 0u);
    if (ok) u = *(const uint4*)(Kt + nbase + (size_t)(gy * WW + gx) * CCH + g * 8);
    kg[r] = u;
  }
#pragma unroll
  for (int r = 0; r < ARND; r++) {
    int s = t + r * 256;
    int pix = s >> 2, g = s & 3;
    int hy = pix / HX, hx = pix - hy * HX;
    int gx = x0 - 1 + hx, gy = y0 - 1 + hy;
    bool ok = (s < NGR) & (gx >= 0) & (gx < WW) & (gy >= 0) & (gy < HH);
    uint4 u = make_uint4(0u, 0u, 0u, 0u);
    if (ok) u = *(const uint4*)(Vt + nbase + (size_t)(gy * WW + gx) * CCH + g * 8);
    vg[r] = u;
  }
  uint4 q0 = *(const uint4*)(Qt + pixhalf);
  uint4 q1 = *(const uint4*)(Qt + pixhalf + 8);

#pragma unroll
  for (int r = 0; r < ARND; r++) {
    int s = t + r * 256;
    if (s < NGR) {
      int pix = s >> 2, g = s & 3;
      *(uint4*)(&kl[pix * 32 + (((g + (pix >> 1)) & 3) << 3)]) = kg[r];
    }
  }
#pragma unroll
  for (int r = 0; r < ARND; r++) {
    int s = t + r * 256;
    if (s < NGR) {
      int pix = s >> 2, g = s & 3;
      *(uint4*)(&vl[pix * 32 + (((g + (pix >> 1)) & 3) << 3)]) = vg[r];
    }
  }
  __syncthreads();

  float qh[16];
  qh[0] = bf2f(q0.x & 0xffffu); qh[1] = bf2f(q0.x >> 16);
  qh[2] = bf2f(q0.y & 0xffffu); qh[3] = bf2f(q0.y >> 16);
  qh[4] = bf2f(q0.z & 0xffffu); qh[5] = bf2f(q0.z >> 16);
  qh[6] = bf2f(q0.w & 0xffffu); qh[7] = bf2f(q0.w >> 16);
  qh[8] = bf2f(q1.x & 0xffffu); qh[9] = bf2f(q1.x >> 16);
  qh[10] = bf2f(q1.y & 0xffffu); qh[11] = bf2f(q1.y >> 16);
  qh[12] = bf2f(q1.z & 0xffffu); qh[13] = bf2f(q1.z >> 16);
  qh[14] = bf2f(q1.w & 0xffffu); qh[15] = bf2f(q1.w >> 16);

  float f[9];
#pragma unroll
  for (int kk = 0; kk < 9; kk++) {
    int pix = (ly + kk / 3) * HX + lx + kk % 3;
    int ga = h2 * 2;
    uint4 ka = *(const uint4*)(&kl[pix * 32 + (((ga + (pix >> 1)) & 3) << 3)]);
    uint4 kb = *(const uint4*)(&kl[pix * 32 + (((ga + 1 + (pix >> 1)) & 3) << 3)]);
    float s = 0.f;
    fma8(ka, qh, s);
    fma8(kb, qh + 8, s);
    f[kk] = s + __shfl_xor(s, 32, 64);
  }

  float g[9], m = -1e30f;
#pragma unroll
  for (int k2 = 0; k2 < 9; k2++) {
    float s = 0.f;
#pragma unroll
    for (int kk = 0; kk < 9; kk++) s = fmaf(coef[k2 * 9 + kk], f[kk], s);
    g[k2] = s;
    m = fmaxf(m, s);
  }
  float ssum = 0.f;
#pragma unroll
  for (int k2 = 0; k2 < 9; k2++) {
    g[k2] = __expf(g[k2] - m);
    ssum += g[k2];
  }
  float inv = 1.f / ssum;
#pragma unroll
  for (int k2 = 0; k2 < 9; k2++) g[k2] *= inv;

  float oh[16];
#pragma unroll
  for (int j = 0; j < 16; j++) oh[j] = 0.f;
#pragma unroll
  for (int kk = 0; kk < 9; kk++) {
    int pix = (ly + kk / 3) * HX + lx + kk % 3;
    int ga = h2 * 2;
    uint4 va = *(const uint4*)(&vl[pix * 32 + (((ga + (pix >> 1)) & 3) << 3)]);
    uint4 vb = *(const uint4*)(&vl[pix * 32 + (((ga + 1 + (pix >> 1)) & 3) << 3)]);
    acc8(va, g[kk], oh);
    acc8(vb, g[kk], oh + 8);
  }
  uint4 s0, s1;
  s0.x = (unsigned)f2bf(oh[0]) | ((unsigned)f2bf(oh[1]) << 16);
  s0.y = (unsigned)f2bf(oh[2]) | ((unsigned)f2bf(oh[3]) << 16);
  s0.z = (unsigned)f2bf(oh[4]) | ((unsigned)f2bf(oh[5]) << 16);
  s0.w = (unsigned)f2bf(oh[6]) | ((unsigned)f2bf(oh[7]) << 16);
  s1.x = (unsigned)f2bf(oh[8]) | ((unsigned)f2bf(oh[9]) << 16);
  s1.y = (unsigned)f2bf(oh[10]) | ((unsigned)f2bf(oh[11]) << 16);
  s1.z = (unsigned)f2bf(oh[12]) | ((unsigned)f2bf(oh[13]) << 16);
  s1.w = (unsigned)f2bf(oh[14]) | ((unsigned)f2bf(oh[15]) << 16);
  *(uint4*)(Qt + pixhalf) = s0;
  *(uint4*)(Qt + pixhalf + 8) = s1;
}

// ---------------------------------------------------------------------------
extern "C" void kernel_launch(void* const* d_in, const int* in_sizes, int n_in,
                              void* d_out, int out_size, void* d_ws, size_t ws_size,
                              hipStream_t stream) {
  const float* q     = (const float*)d_in[0];
  const float* k     = (const float*)d_in[1];
  const float* v     = (const float*)d_in[2];
  const float* wq    = (const float*)d_in[3];
  const float* pe_dw = (const float*)d_in[4];
  const float* pe_pw = (const float*)d_in[5];
  const float* wo    = (const float*)d_in[6];
  const float* bo    = (const float*)d_in[7];
  float* out = (float*)d_out;

  const size_t seg = (size_t)BB * PP * CCH;
  u16* Xcl = (u16*)d_ws;                 // 3*seg bf16: q,k,v projections
  u16* Wbf = Xcl + 3 * seg;              // 131072 bf16: W2(wq) | W2(wo)

  wcvt<<<64, 256, 0, stream>>>(wq, wo, Wbf);

  gemm_qkvf<<<dim3(PP / 64, 1, 12), 256, 0, stream>>>(q, k, v, Wbf, Xcl);

  u16* Qs = Xcl;
  u16* Ks = Xcl + seg;
  u16* Vs = Xcl + 2 * seg;
  attn_1b<<<dim3(WW / TX, HH / TY, BB * 8), 256, 0, stream>>>(Ks, Vs, Qs, pe_dw, pe_pw);

  gemm_out_m<<<dim3(PP / 64, 1, BB), 256, 0, stream>>>(Qs, Wbf + 65536, bo, out);
}

// Round 10
// 88.271 us; speedup vs baseline: 1.0921x; 1.0244x over previous
//
#include <hip/hip_runtime.h>
#include <math.h>

#define HH 96
#define WW 96
#define PP 9216   // H*W
#define CCH 256
#define BB 4
#define CH 32

typedef unsigned short u16;
typedef short bf16x8 __attribute__((ext_vector_type(8)));
typedef float f32x4 __attribute__((ext_vector_type(4)));

__device__ __forceinline__ float bf2f(unsigned s) { return __uint_as_float(s << 16); }
__device__ __forceinline__ u16 f2bf(float f) {
  unsigned u = __float_as_uint(f);
  return (u16)((u + 0x7fffu + ((u >> 16) & 1u)) >> 16);
}

typedef __attribute__((address_space(1))) const unsigned int GUI;
typedef __attribute__((address_space(3))) unsigned int LUI;
__device__ __forceinline__ void gload16(const void* g, void* l) {
  __builtin_amdgcn_global_load_lds((GUI*)g, (LUI*)l, 16, 0, 0);
}

// ---------------------------------------------------------------------------
// wcvt: W -> bf16 in per-lane FRAGMENT order (unchanged from R8/R9).
// go = ((((kk*2+ks)*4+w)*4+i)*64+l)*8 holds row=w*64+i*16+(l&15),
// c = kk*64 + (ks*4+(l>>4))*8 .. +7.
// ---------------------------------------------------------------------------
__global__ __launch_bounds__(256)
void wcvt(const float* __restrict__ wq, const float* __restrict__ wo,
          u16* __restrict__ Wbf) {
  int gidx = blockIdx.x * 256 + threadIdx.x;   // 0..16383
  int mat = gidx >> 13;
  int gi = gidx & 8191;
  int l = gi & 63;
  int i = (gi >> 6) & 3;
  int w = (gi >> 8) & 3;
  int ks = (gi >> 10) & 1;
  int kk = (gi >> 11) & 3;
  const float* W = mat ? wo : wq;
  int row = w * 64 + i * 16 + (l & 15);
  int c0 = kk * 64 + (ks * 4 + (l >> 4)) * 8;
  const float* s = W + (size_t)row * CCH + c0;
  float4 a = *(const float4*)s;
  float4 b = *(const float4*)(s + 4);
  uint4 u;
  u.x = (unsigned)f2bf(a.x) | ((unsigned)f2bf(a.y) << 16);
  u.y = (unsigned)f2bf(a.z) | ((unsigned)f2bf(a.w) << 16);
  u.z = (unsigned)f2bf(b.x) | ((unsigned)f2bf(b.y) << 16);
  u.w = (unsigned)f2bf(b.z) | ((unsigned)f2bf(b.w) << 16);
  *(uint4*)(Wbf + (size_t)gidx * 8) = u;
}

// ---------------------------------------------------------------------------
// Fused projection GEMM v4 — 8 waves (512 thr), single stage, single barrier.
// Per thread: 8 f32x4 loads (all in flight, xr[8]=32 VGPR), shfl 4x4
// transpose + cvt, bf16 LDS write. One barrier. Wave w owns o=w*32..+31:
// acc[2][4]=32 VGPR, 64 MFMA/wave, W direct from L2 (fragment order).
// ---------------------------------------------------------------------------
#define XROW 264
__global__ __launch_bounds__(512, 6)
void gemm_qkvf(const float* __restrict__ qin, const float* __restrict__ kin,
               const float* __restrict__ vin, const u16* __restrict__ Wbf,
               u16* __restrict__ Xcl) {
  __shared__ u16 Xb[64 * XROW];   // 33,792 B
  const int t = threadIdx.x;
  const int w = t >> 6, l = t & 63;
  const int lr = l & 15, lg = l >> 4;
  const int pblk = blockIdx.x * 64;
  const int z = blockIdx.z;
  const int b = z & 3, which = z >> 2;
  const float* Xf = ((which == 0) ? qin : (which == 1) ? kin : vin) + (size_t)b * CCH * PP;
  u16* Y = Xcl + (size_t)z * ((size_t)PP * CCH);

  // ---- stage: 8 loads per thread, wave covers c = w*32 .. w*32+31 ----
  float4 xr[8];
#pragma unroll
  for (int rr = 0; rr < 8; rr++) {
    int cc = w * 32 + rr * 4 + lg;
    xr[rr] = *(const float4*)(Xf + (size_t)cc * PP + pblk + lr * 4);
  }
  // ---- 4x4 lg-group shfl transpose (R7-verified), cvt, LDS write ----
#pragma unroll
  for (int rr = 0; rr < 8; rr++) {
    float r0 = xr[rr].x, r1 = xr[rr].y, r2 = xr[rr].z, r3 = xr[rr].w;
    bool b0 = (lg & 1), b1 = (lg & 2);
    float s0 = b0 ? r0 : r1;
    float s1 = b0 ? r2 : r3;
    float u0 = __shfl_xor(s0, 16, 64);
    float u1 = __shfl_xor(s1, 16, 64);
    float m0 = b0 ? u0 : r0;
    float m1 = b0 ? r1 : u0;
    float m2 = b0 ? u1 : r2;
    float m3 = b0 ? r3 : u1;
    float s2 = b1 ? m0 : m2;
    float s3 = b1 ? m1 : m3;
    float w0 = __shfl_xor(s2, 32, 64);
    float w1 = __shfl_xor(s3, 32, 64);
    float o0 = b1 ? w0 : m0;
    float o1 = b1 ? w1 : m1;
    float o2 = b1 ? m2 : w0;
    float o3 = b1 ? m3 : w1;
    // lane holds c = cbase..cbase+3 of p-row pl
    int cbase = w * 32 + rr * 4;
    int pl = lr * 4 + lg;
    unsigned lo = (unsigned)f2bf(o0) | ((unsigned)f2bf(o1) << 16);
    unsigned hi = (unsigned)f2bf(o2) | ((unsigned)f2bf(o3) << 16);
    *(uint2*)(&Xb[pl * XROW + cbase]) = make_uint2(lo, hi);
  }
  __syncthreads();   // the ONE barrier

  f32x4 acc[2][4];
#pragma unroll
  for (int mi = 0; mi < 2; mi++)
#pragma unroll
    for (int ni = 0; ni < 4; ni++) acc[mi][ni] = (f32x4){0.f, 0.f, 0.f, 0.f};

  // ---- 64 MFMA per wave, no syncs: W from L2 (re-indexed for 8 waves) ----
#pragma unroll
  for (int kk = 0; kk < 4; kk++)
#pragma unroll
    for (int ks = 0; ks < 2; ks++) {
      const int q = kk * 8 + ks * 4 + lg;
      bf16x8 wf[2], xf[4];
#pragma unroll
      for (int mi = 0; mi < 2; mi++) {
        size_t go = ((((size_t)(kk * 2 + ks) * 4 + (w >> 1)) * 4 +
                      ((w & 1) * 2 + mi)) * 64 + l) * 8;
        wf[mi] = *(const bf16x8*)(Wbf + go);
      }
#pragma unroll
      for (int i = 0; i < 4; i++) {
        int row = i * 16 + lr;
        xf[i] = *(const bf16x8*)&Xb[row * XROW + q * 8];
      }
#pragma unroll
      for (int mi = 0; mi < 2; mi++)
#pragma unroll
        for (int ni = 0; ni < 4; ni++)
          acc[mi][ni] = __builtin_amdgcn_mfma_f32_16x16x32_bf16(
              wf[mi], xf[ni], acc[mi][ni], 0, 0, 0);
    }

  // epilogue: D[o][p] -> bf16 channel-last
#pragma unroll
  for (int mi = 0; mi < 2; mi++)
#pragma unroll
    for (int ni = 0; ni < 4; ni++) {
      int o = w * 32 + mi * 16 + lg * 4;
      int p = pblk + ni * 16 + lr;
      f32x4 a = acc[mi][ni];
      uint2 u;
      u.x = (unsigned)f2bf(a[0]) | ((unsigned)f2bf(a[1]) << 16);
      u.y = (unsigned)f2bf(a[2]) | ((unsigned)f2bf(a[3]) << 16);
      *(uint2*)(Y + (size_t)p * CCH + o) = u;
    }
}

// ---------------------------------------------------------------------------
// Out-projection GEMM v3 (unchanged from R9 — at HBM floor).
// ---------------------------------------------------------------------------
__global__ __launch_bounds__(256)
void gemm_out_m(const u16* __restrict__ Xbuf, const u16* __restrict__ Wbf,
                const float* __restrict__ bias, float* __restrict__ outY) {
  __shared__ u16 Xl[64 * 256];   // 32 KB
  const int t = threadIdx.x;
  const int w = t >> 6, l = t & 63;
  const int lr = l & 15, lg = l >> 4;
  const int pblk = blockIdx.x * 64;
  const int z = blockIdx.z;
  const u16* Xb = Xbuf + (size_t)z * ((size_t)PP * CCH);

#pragma unroll
  for (int r = 0; r < 8; r++) {
    int G = r * 256 + t;
    int row = G >> 5, g = G & 31;
    int gs = (g & 24) | ((g & 7) ^ (row & 7));
    gload16(Xb + (size_t)(pblk + row) * CCH + gs * 8, (void*)&Xl[(size_t)G * 8]);
  }
  __syncthreads();

  f32x4 acc[4][4];
#pragma unroll
  for (int mi = 0; mi < 4; mi++)
#pragma unroll
    for (int ni = 0; ni < 4; ni++) acc[mi][ni] = (f32x4){0.f, 0.f, 0.f, 0.f};

#pragma unroll
  for (int kk = 0; kk < 4; kk++)
#pragma unroll
    for (int ks = 0; ks < 2; ks++) {
      const int q = kk * 8 + ks * 4 + lg;
      bf16x8 wf[4], xf[4];
#pragma unroll
      for (int i = 0; i < 4; i++) {
        size_t go = ((((size_t)(kk * 2 + ks) * 4 + w) * 4 + i) * 64 + l) * 8;
        wf[i] = *(const bf16x8*)(Wbf + go);
      }
#pragma unroll
      for (int i = 0; i < 4; i++) {
        int row = i * 16 + lr;
        int qp = (q & 24) | ((q & 7) ^ (row & 7));
        xf[i] = *(const bf16x8*)&Xl[row * 256 + qp * 8];
      }
#pragma unroll
      for (int mi = 0; mi < 4; mi++)
#pragma unroll
        for (int ni = 0; ni < 4; ni++)
          acc[mi][ni] = __builtin_amdgcn_mfma_f32_16x16x32_bf16(
              xf[mi], wf[ni], acc[mi][ni], 0, 0, 0);
    }

#pragma unroll
  for (int ni = 0; ni < 4; ni++) {
    int o = w * 64 + ni * 16 + lr;
    float bv = bias[o];
#pragma unroll
    for (int mi = 0; mi < 4; mi++) {
      int p = pblk + mi * 16 + lg * 4;
      f32x4 a = acc[mi][ni];
      float4 st = {a[0] + bv, a[1] + bv, a[2] + bv, a[3] + bv};
      *(float4*)(outY + ((size_t)z * CCH + o) * PP + p) = st;
    }
  }
}

// ---------------------------------------------------------------------------
// Attention, single-barrier (unchanged from R7 — ~14 us).
// ---------------------------------------------------------------------------
#define TX 32
#define TY 4
#define HX 34
#define HY 6
#define NHP (HX * HY)
#define NGR (NHP * 4)
#define ARND 4

__device__ __forceinline__ void fma8(const uint4 u, const float* qp, float& s) {
  s = fmaf(qp[0], bf2f(u.x & 0xffffu), s);
  s = fmaf(qp[1], bf2f(u.x >> 16), s);
  s = fmaf(qp[2], bf2f(u.y & 0xffffu), s);
  s = fmaf(qp[3], bf2f(u.y >> 16), s);
  s = fmaf(qp[4], bf2f(u.z & 0xffffu), s);
  s = fmaf(qp[5], bf2f(u.z >> 16), s);
  s = fmaf(qp[6], bf2f(u.w & 0xffffu), s);
  s = fmaf(qp[7], bf2f(u.w >> 16), s);
}
__device__ __forceinline__ void acc8(const uint4 u, float gv, float* op) {
  op[0] = fmaf(gv, bf2f(u.x & 0xffffu), op[0]);
  op[1] = fmaf(gv, bf2f(u.x >> 16), op[1]);
  op[2] = fmaf(gv, bf2f(u.y & 0xffffu), op[2]);
  op[3] = fmaf(gv, bf2f(u.y >> 16), op[3]);
  op[4] = fmaf(gv, bf2f(u.z & 0xffffu), op[4]);
  op[5] = fmaf(gv, bf2f(u.z >> 16), op[5]);
  op[6] = fmaf(gv, bf2f(u.w & 0xffffu), op[6]);
  op[7] = fmaf(gv, bf2f(u.w >> 16), op[7]);
}

__global__ __launch_bounds__(256)
void attn_1b(const u16* __restrict__ Kt, const u16* __restrict__ Vt,
             u16* __restrict__ Qt, const float* __restrict__ pe_dw,
             const float* __restrict__ pe_pw) {
  __shared__ __align__(16) u16 kl[NHP * 32];
  __shared__ __align__(16) u16 vl[NHP * 32];
  __shared__ float coef[81];
  const int t = threadIdx.x;
  if (t < 81) coef[t] = pe_pw[t] * pe_dw[t % 9];

  const int lx = t & 31;
  const int h2 = (t >> 5) & 1;
  const int ly = t >> 6;
  const int x0 = blockIdx.x * TX;
  const int y0 = blockIdx.y * TY;
  const int b = blockIdx.z >> 3;
  const int h = blockIdx.z & 7;
  const size_t nbase = (size_t)b * PP * CCH + h * CH;
  const int p = (y0 + ly) * WW + (x0 + lx);
  const size_t pixhalf = nbase + (size_t)p * CCH + h2 * 16;

  uint4 kg[ARND], vg[ARND];
#pragma unroll
  for (int r = 0; r < ARND; r++) {
    int s = t + r * 256;
    int pix = s >> 2, g = s & 3;
    int hy = pix / HX, hx = pix - hy * HX;
    int gx = x0 - 1 + hx, gy = y0 - 1 + hy;
    bool ok = (s < NGR) & (gx >= 0) & (gx < WW) & (gy >= 0) & (gy < HH);
    uint4 u = make_uint4(0u, 0u, 0u, 0u);
    if (ok) u = *(const uint4*)(Kt + nbase + (size_t)(gy * WW + gx) * CCH + g * 8);
    kg[r] = u;
  }
#pragma unroll
  for (int r = 0; r < ARND; r++) {
    int s = t + r * 256;
    int pix = s >> 2, g = s & 3;
    int hy = pix / HX, hx = pix - hy * HX;
    int gx = x0 - 1 + hx, gy = y0 - 1 + hy;
    bool ok = (s < NGR) & (gx >= 0) & (gx < WW) & (gy >= 0) & (gy < HH);
    uint4 u = make_uint4(0u, 0u, 0u, 0u);
    if (ok) u = *(const uint4*)(Vt + nbase + (size_t)(gy * WW + gx) * CCH + g * 8);
    vg[r] = u;
  }
  uint4 q0 = *(const uint4*)(Qt + pixhalf);
  uint4 q1 = *(const uint4*)(Qt + pixhalf + 8);

#pragma unroll
  for (int r = 0; r < ARND; r++) {
    int s = t + r * 256;
    if (s < NGR) {
      int pix = s >> 2, g = s & 3;
      *(uint4*)(&kl[pix * 32 + (((g + (pix >> 1)) & 3) << 3)]) = kg[r];
    }
  }
#pragma unroll
  for (int r = 0; r < ARND; r++) {
    int s = t + r * 256;
    if (s < NGR) {
      int pix = s >> 2, g = s & 3;
      *(uint4*)(&vl[pix * 32 + (((g + (pix >> 1)) & 3) << 3)]) = vg[r];
    }
  }
  __syncthreads();

  float qh[16];
  qh[0] = bf2f(q0.x & 0xffffu); qh[1] = bf2f(q0.x >> 16);
  qh[2] = bf2f(q0.y & 0xffffu); qh[3] = bf2f(q0.y >> 16);
  qh[4] = bf2f(q0.z & 0xffffu); qh[5] = bf2f(q0.z >> 16);
  qh[6] = bf2f(q0.w & 0xffffu); qh[7] = bf2f(q0.w >> 16);
  qh[8] = bf2f(q1.x & 0xffffu); qh[9] = bf2f(q1.x >> 16);
  qh[10] = bf2f(q1.y & 0xffffu); qh[11] = bf2f(q1.y >> 16);
  qh[12] = bf2f(q1.z & 0xffffu); qh[13] = bf2f(q1.z >> 16);
  qh[14] = bf2f(q1.w & 0xffffu); qh[15] = bf2f(q1.w >> 16);

  float f[9];
#pragma unroll
  for (int kk = 0; kk < 9; kk++) {
    int pix = (ly + kk / 3) * HX + lx + kk % 3;
    int ga = h2 * 2;
    uint4 ka = *(const uint4*)(&kl[pix * 32 + (((ga + (pix >> 1)) & 3) << 3)]);
    uint4 kb = *(const uint4*)(&kl[pix * 32 + (((ga + 1 + (pix >> 1)) & 3) << 3)]);
    float s = 0.f;
    fma8(ka, qh, s);
    fma8(kb, qh + 8, s);
    f[kk] = s + __shfl_xor(s, 32, 64);
  }

  float g[9], m = -1e30f;
#pragma unroll
  for (int k2 = 0; k2 < 9; k2++) {
    float s = 0.f;
#pragma unroll
    for (int kk = 0; kk < 9; kk++) s = fmaf(coef[k2 * 9 + kk], f[kk], s);
    g[k2] = s;
    m = fmaxf(m, s);
  }
  float ssum = 0.f;
#pragma unroll
  for (int k2 = 0; k2 < 9; k2++) {
    g[k2] = __expf(g[k2] - m);
    ssum += g[k2];
  }
  float inv = 1.f / ssum;
#pragma unroll
  for (int k2 = 0; k2 < 9; k2++) g[k2] *= inv;

  float oh[16];
#pragma unroll
  for (int j = 0; j < 16; j++) oh[j] = 0.f;
#pragma unroll
  for (int kk = 0; kk < 9; kk++) {
    int pix = (ly + kk / 3) * HX + lx + kk % 3;
    int ga = h2 * 2;
    uint4 va = *(const uint4*)(&vl[pix * 32 + (((ga + (pix >> 1)) & 3) << 3)]);
    uint4 vb = *(const uint4*)(&vl[pix * 32 + (((ga + 1 + (pix >> 1)) & 3) << 3)]);
    acc8(va, g[kk], oh);
    acc8(vb, g[kk], oh + 8);
  }
  uint4 s0, s1;
  s0.x = (unsigned)f2bf(oh[0]) | ((unsigned)f2bf(oh[1]) << 16);
  s0.y = (unsigned)f2bf(oh[2]) | ((unsigned)f2bf(oh[3]) << 16);
  s0.z = (unsigned)f2bf(oh[4]) | ((unsigned)f2bf(oh[5]) << 16);
  s0.w = (unsigned)f2bf(oh[6]) | ((unsigned)f2bf(oh[7]) << 16);
  s1.x = (unsigned)f2bf(oh[8]) | ((unsigned)f2bf(oh[9]) << 16);
  s1.y = (unsigned)f2bf(oh[10]) | ((unsigned)f2bf(oh[11]) << 16);
  s1.z = (unsigned)f2bf(oh[12]) | ((unsigned)f2bf(oh[13]) << 16);
  s1.w = (unsigned)f2bf(oh[14]) | ((unsigned)f2bf(oh[15]) << 16);
  *(uint4*)(Qt + pixhalf) = s0;
  *(uint4*)(Qt + pixhalf + 8) = s1;
}

// ---------------------------------------------------------------------------
extern "C" void kernel_launch(void* const* d_in, const int* in_sizes, int n_in,
                              void* d_out, int out_size, void* d_ws, size_t ws_size,
                              hipStream_t stream) {
  const float* q     = (const float*)d_in[0];
  const float* k     = (const float*)d_in[1];
  const float* v     = (const float*)d_in[2];
  const float* wq    = (const float*)d_in[3];
  const float* pe_dw = (const float*)d_in[4];
  const float* pe_pw = (const float*)d_in[5];
  const float* wo    = (const float*)d_in[6];
  const float* bo    = (const float*)d_in[7];
  float* out = (float*)d_out;

  const size_t seg = (size_t)BB * PP * CCH;
  u16* Xcl = (u16*)d_ws;                 // 3*seg bf16: q,k,v projections
  u16* Wbf = Xcl + 3 * seg;              // 131072 bf16: W2(wq) | W2(wo)

  wcvt<<<64, 256, 0, stream>>>(wq, wo, Wbf);

  gemm_qkvf<<<dim3(PP / 64, 1, 12), 512, 0, stream>>>(q, k, v, Wbf, Xcl);

  u16* Qs = Xcl;
  u16* Ks = Xcl + seg;
  u16* Vs = Xcl + 2 * seg;
  attn_1b<<<dim3(WW / TX, HH / TY, BB * 8), 256, 0, stream>>>(Ks, Vs, Qs, pe_dw, pe_pw);

  gemm_out_m<<<dim3(PP / 64, 1, BB), 256, 0, stream>>>(Qs, Wbf + 65536, bo, out);
}